// Round 1
// baseline (1254.849 us; speedup 1.0000x reference)
//
#include <hip/hip_runtime.h>
#include <hip/hip_bf16.h>
#include <math.h>

#define N_NODES 100000
#define N_EDGES 1600000
#define N_FEAT 75
#define HID 64
#define NUM_GRAPHS 4096
#define BN_EPS 1e-5f
#define NSLICE 256

// ---------------- setup: degree, norms, CSR build ----------------

__global__ void count_kernel(const int* __restrict__ dst, int* __restrict__ cnt) {
  int e = blockIdx.x * blockDim.x + threadIdx.x;
  if (e < N_EDGES) atomicAdd(&cnt[dst[e]], 1);
}

__global__ void dinv_kernel(const int* __restrict__ cnt, float* __restrict__ dinv) {
  int v = blockIdx.x * blockDim.x + threadIdx.x;
  if (v < N_NODES) dinv[v] = rsqrtf((float)cnt[v] + 1.0f);
}

// exclusive scan of cnt[0..N) into rowptr[0..N); 1024 elems/block
__global__ void scan1_kernel(const int* __restrict__ in, int* __restrict__ out,
                             int* __restrict__ bsum) {
  __shared__ int ls[256];
  int t = threadIdx.x;
  int base = blockIdx.x * 1024 + t * 4;
  int a0 = (base + 0 < N_NODES) ? in[base + 0] : 0;
  int a1 = (base + 1 < N_NODES) ? in[base + 1] : 0;
  int a2 = (base + 2 < N_NODES) ? in[base + 2] : 0;
  int a3 = (base + 3 < N_NODES) ? in[base + 3] : 0;
  ls[t] = a0 + a1 + a2 + a3;
  __syncthreads();
  for (int off = 1; off < 256; off <<= 1) {
    int add = (t >= off) ? ls[t - off] : 0;
    __syncthreads();
    ls[t] += add;
    __syncthreads();
  }
  int excl = (t > 0) ? ls[t - 1] : 0;
  if (base + 0 < N_NODES) out[base + 0] = excl;
  if (base + 1 < N_NODES) out[base + 1] = excl + a0;
  if (base + 2 < N_NODES) out[base + 2] = excl + a0 + a1;
  if (base + 3 < N_NODES) out[base + 3] = excl + a0 + a1 + a2;
  if (t == 255) bsum[blockIdx.x] = ls[255];
}

__global__ void scan2_kernel(int* bsum, int nb) {
  if (threadIdx.x == 0 && blockIdx.x == 0) {
    int a = 0;
    for (int i = 0; i < nb; ++i) { int v = bsum[i]; bsum[i] = a; a += v; }
  }
}

__global__ void scan3_kernel(int* __restrict__ out, const int* __restrict__ bsum) {
  int t = threadIdx.x;
  int base = blockIdx.x * 1024 + t * 4;
  int add = bsum[blockIdx.x];
  #pragma unroll
  for (int i = 0; i < 4; ++i)
    if (base + i < N_NODES) out[base + i] += add;
  if (blockIdx.x == 0 && t == 0) out[N_NODES] = N_EDGES;
}

// scatter edges into CSR slots; also accumulate Ssum[v] = sum of incoming edge_norm
__global__ void fill_kernel(const int* __restrict__ src, const int* __restrict__ dst,
                            const float* __restrict__ dinv, int* __restrict__ pos,
                            int2* __restrict__ csr, float* __restrict__ Ssum) {
  int e = blockIdx.x * blockDim.x + threadIdx.x;
  if (e >= N_EDGES) return;
  int s = src[e], d = dst[e];
  float w = dinv[s] * dinv[d];
  int p = atomicAdd(&pos[d], 1);
  csr[p] = make_int2(s, __float_as_int(w));
  atomicAdd(&Ssum[d], w);
}

__global__ void finS_kernel(const float* __restrict__ dinv, float* __restrict__ Ssum) {
  int v = blockIdx.x * blockDim.x + threadIdx.x;
  if (v < N_NODES) Ssum[v] += dinv[v] * dinv[v];
}

// ---------------- per-layer GEMM: H[N,64] = X[N,K] @ W[K,64] ----------------

__global__ __launch_bounds__(256) void gemm_kernel(
    const float* __restrict__ X, const float* __restrict__ W,
    float* __restrict__ Hout, int K) {
  __shared__ float xs[64][81];   // [row][k], pad 81 to break 4-way bank conflict
  __shared__ float ws[80][64];   // [k][col], row stride 256B keeps float4 align
  int t = threadIdx.x;
  int rowBase = blockIdx.x * 64;
  for (int i = t; i < K * 64; i += 256) ws[i >> 6][i & 63] = W[i];
  for (int i = t; i < 64 * K; i += 256) {
    int r = i / K, k = i - r * K;
    int row = rowBase + r;
    xs[r][k] = (row < N_NODES) ? X[(size_t)row * K + k] : 0.f;
  }
  __syncthreads();
  int ty = t >> 4, tx = t & 15;
  int r0 = ty * 4, c0 = tx * 4;
  float acc[4][4] = {};
  for (int k = 0; k < K; ++k) {
    float4 bq = *(const float4*)&ws[k][c0];
    float bv[4] = {bq.x, bq.y, bq.z, bq.w};
    float av[4] = {xs[r0][k], xs[r0 + 1][k], xs[r0 + 2][k], xs[r0 + 3][k]};
    #pragma unroll
    for (int i = 0; i < 4; ++i)
      #pragma unroll
      for (int j = 0; j < 4; ++j)
        acc[i][j] = fmaf(av[i], bv[j], acc[i][j]);
  }
  #pragma unroll
  for (int i = 0; i < 4; ++i) {
    int row = rowBase + r0 + i;
    if (row < N_NODES)
      *(float4*)&Hout[(size_t)row * HID + c0] =
          make_float4(acc[i][0], acc[i][1], acc[i][2], acc[i][3]);
  }
}

// ---------------- aggregation + relu + BN-stats ----------------
// z[v] = relu( sum_in w_e*H[src] + dinv^2*H[v] + S[v]*c + b );  stats += (z, z^2)

#define AGG_WAVES 8
#define AGG_NPW 8

__global__ __launch_bounds__(512) void agg_kernel(
    const float* __restrict__ H, const int2* __restrict__ csr,
    const int* __restrict__ rowptr, const float* __restrict__ S,
    const float* __restrict__ dinv, const float* __restrict__ cvec,
    const float* __restrict__ bias, float* __restrict__ Z,
    float* __restrict__ stats) {
  int t = threadIdx.x;
  int wave = t >> 6, lane = t & 63;
  int nodeBase = blockIdx.x * (AGG_WAVES * AGG_NPW) + wave * AGG_NPW;
  float cl = cvec[lane], bl = bias[lane];
  float ssum = 0.f, ssq = 0.f;
  for (int i = 0; i < AGG_NPW; ++i) {
    int v = nodeBase + i;
    if (v >= N_NODES) break;
    float dv = dinv[v];
    float acc = H[(size_t)v * HID + lane] * (dv * dv);
    int e0 = rowptr[v], e1 = rowptr[v + 1];
    for (int e = e0; e < e1; ++e) {
      int2 p = csr[e];
      acc = fmaf(__int_as_float(p.y), H[(size_t)p.x * HID + lane], acc);
    }
    float z = acc + S[v] * cl + bl;
    z = fmaxf(z, 0.f);
    Z[(size_t)v * HID + lane] = z;
    ssum += z; ssq += z * z;
  }
  __shared__ float redS[AGG_WAVES][64];
  __shared__ float redQ[AGG_WAVES][64];
  redS[wave][lane] = ssum;
  redQ[wave][lane] = ssq;
  __syncthreads();
  if (wave == 0) {
    float s = 0.f, q = 0.f;
    #pragma unroll
    for (int i = 0; i < AGG_WAVES; ++i) { s += redS[i][lane]; q += redQ[i][lane]; }
    float* sl = stats + (size_t)(blockIdx.x & (NSLICE - 1)) * 128;
    atomicAdd(&sl[lane], s);
    atomicAdd(&sl[64 + lane], q);
  }
}

// ---------------- BN fold: alpha/beta, W' = alpha⊙W_next, c = beta@W_next ----

__global__ __launch_bounds__(256) void prep_kernel(
    const float* __restrict__ stats, const float* __restrict__ g,
    const float* __restrict__ be, const float* __restrict__ Wnext,
    float* __restrict__ Wp, float* __restrict__ cvec,
    float* __restrict__ ab, int hasNext) {
  __shared__ float tmp[128];
  __shared__ float alpha[64];
  __shared__ float beta[64];
  int t = threadIdx.x;
  if (t < 128) {
    float s = 0.f;
    for (int i = 0; i < NSLICE; ++i) s += stats[(size_t)i * 128 + t];
    tmp[t] = s;
  }
  __syncthreads();
  if (t < 64) {
    float m = tmp[t] / (float)N_NODES;
    float var = tmp[64 + t] / (float)N_NODES - m * m;
    float a = g[t] * rsqrtf(var + BN_EPS);
    alpha[t] = a;
    float bt = be[t] - m * a;
    beta[t] = bt;
    ab[t] = a;
    ab[64 + t] = bt;
  }
  __syncthreads();
  if (hasNext) {
    for (int i = t; i < HID * HID; i += 256) Wp[i] = alpha[i >> 6] * Wnext[i];
    if (t < 64) {
      float c = 0.f;
      for (int k = 0; k < HID; ++k) c += beta[k] * Wnext[k * HID + t];
      cvec[t] = c;
    }
  }
}

// ---------------- pool: out[g] += BN(z4)[v] for v in graph g (batch sorted) ----

#define POOL_CH 32

__global__ __launch_bounds__(256) void pool_kernel(
    const float* __restrict__ Z, const int* __restrict__ batch,
    const float* __restrict__ ab, float* __restrict__ out) {
  int tid = blockIdx.x * blockDim.x + threadIdx.x;
  int w = tid >> 6, lane = tid & 63;
  int v0 = w * POOL_CH;
  if (v0 >= N_NODES) return;
  int v1 = min(N_NODES, v0 + POOL_CH);
  float a = ab[lane], b = ab[64 + lane];
  float acc = 0.f;
  int cur = batch[v0];
  for (int v = v0; v < v1; ++v) {
    int bg = batch[v];
    if (bg != cur) {
      atomicAdd(&out[(size_t)cur * HID + lane], acc);
      acc = 0.f;
      cur = bg;
    }
    acc = fmaf(Z[(size_t)v * HID + lane], a, acc + b);
  }
  atomicAdd(&out[(size_t)cur * HID + lane], acc);
}

// ---------------- launch ----------------

extern "C" void kernel_launch(void* const* d_in, const int* in_sizes, int n_in,
                              void* d_out, int out_size, void* d_ws, size_t ws_size,
                              hipStream_t stream) {
  const float* x    = (const float*)d_in[0];
  const int* src    = (const int*)d_in[1];
  const int* dst    = (const int*)d_in[2];
  const int* batch  = (const int*)d_in[3];
  const float* W[4]  = {(const float*)d_in[4], (const float*)d_in[8],
                        (const float*)d_in[12], (const float*)d_in[16]};
  const float* b[4]  = {(const float*)d_in[5], (const float*)d_in[9],
                        (const float*)d_in[13], (const float*)d_in[17]};
  const float* g[4]  = {(const float*)d_in[6], (const float*)d_in[10],
                        (const float*)d_in[14], (const float*)d_in[18]};
  const float* be[4] = {(const float*)d_in[7], (const float*)d_in[11],
                        (const float*)d_in[15], (const float*)d_in[19]};

  char* wsb = (char*)d_ws;
  size_t off = 0;
  auto alloc = [&](size_t bytes) -> void* {
    void* p = wsb + off;
    off += (bytes + 255) & ~(size_t)255;
    return p;
  };
  // zeroed region (one memset)
  int*   cnt    = (int*)  alloc((N_NODES + 1) * 4);
  float* Ssum   = (float*)alloc((size_t)N_NODES * 4);
  float* c0     = (float*)alloc(64 * 4);
  float* stats  = (float*)alloc((size_t)4 * NSLICE * 128 * 4);
  size_t zero_bytes = off;
  // non-zeroed
  int*   rowptr = (int*)  alloc((size_t)(N_NODES + 1) * 4);
  int*   pos    = (int*)  alloc((size_t)N_NODES * 4);
  int*   bsum   = (int*)  alloc(128 * 4);
  float* dinv   = (float*)alloc((size_t)N_NODES * 4);
  int2*  csr    = (int2*) alloc((size_t)N_EDGES * 8);
  float* Hb     = (float*)alloc((size_t)N_NODES * HID * 4);
  float* Zb     = (float*)alloc((size_t)N_NODES * HID * 4);
  float* Wp     = (float*)alloc(HID * HID * 4);
  float* cv     = (float*)alloc(64 * 4);
  float* ab     = (float*)alloc(128 * 4);

  hipMemsetAsync(d_ws, 0, zero_bytes, stream);
  hipMemsetAsync(d_out, 0, (size_t)out_size * 4, stream);

  count_kernel<<<(N_EDGES + 255) / 256, 256, 0, stream>>>(dst, cnt);
  dinv_kernel<<<(N_NODES + 255) / 256, 256, 0, stream>>>(cnt, dinv);
  int nscan = (N_NODES + 1023) / 1024;
  scan1_kernel<<<nscan, 256, 0, stream>>>(cnt, rowptr, bsum);
  scan2_kernel<<<1, 64, 0, stream>>>(bsum, nscan);
  scan3_kernel<<<nscan, 256, 0, stream>>>(rowptr, bsum);
  hipMemcpyAsync(pos, rowptr, (size_t)N_NODES * 4, hipMemcpyDeviceToDevice, stream);
  fill_kernel<<<(N_EDGES + 255) / 256, 256, 0, stream>>>(src, dst, dinv, pos, csr, Ssum);
  finS_kernel<<<(N_NODES + 255) / 256, 256, 0, stream>>>(dinv, Ssum);

  int gemmBlocks = (N_NODES + 63) / 64;
  int aggBlocks  = (N_NODES + AGG_WAVES * AGG_NPW - 1) / (AGG_WAVES * AGG_NPW);

  // layer 1 (K=75, c=0)
  gemm_kernel<<<gemmBlocks, 256, 0, stream>>>(x, W[0], Hb, N_FEAT);
  agg_kernel<<<aggBlocks, 512, 0, stream>>>(Hb, csr, rowptr, Ssum, dinv, c0, b[0], Zb, stats);
  prep_kernel<<<1, 256, 0, stream>>>(stats, g[0], be[0], W[1], Wp, cv, ab, 1);

  // layers 2..4
  for (int l = 1; l < 4; ++l) {
    gemm_kernel<<<gemmBlocks, 256, 0, stream>>>(Zb, Wp, Hb, HID);
    agg_kernel<<<aggBlocks, 512, 0, stream>>>(Hb, csr, rowptr, Ssum, dinv, cv, b[l], Zb,
                                              stats + (size_t)l * NSLICE * 128);
    prep_kernel<<<1, 256, 0, stream>>>(stats + (size_t)l * NSLICE * 128, g[l], be[l],
                                       (l < 3) ? W[l + 1] : nullptr, Wp, cv, ab,
                                       (l < 3) ? 1 : 0);
  }

  int poolBlocks = (N_NODES + 4 * POOL_CH - 1) / (4 * POOL_CH);
  pool_kernel<<<poolBlocks, 256, 0, stream>>>(Zb, batch, ab, (float*)d_out);
}

// Round 2
// 720.999 us; speedup vs baseline: 1.7404x; 1.7404x over previous
//
#include <hip/hip_runtime.h>
#include <hip/hip_bf16.h>
#include <math.h>

#define N_NODES 100000
#define N_EDGES 1600000
#define N_FEAT 75
#define HID 64
#define NUM_GRAPHS 4096
#define BN_EPS 1e-5f
#define NSLICE 64

// ---------------- setup: degree, norms, CSR build ----------------

__global__ void count_kernel(const int* __restrict__ dst, int* __restrict__ cnt) {
  int i = (blockIdx.x * blockDim.x + threadIdx.x) * 4;
  if (i + 4 <= N_EDGES) {
    int4 d = *(const int4*)&dst[i];
    atomicAdd(&cnt[d.x], 1);
    atomicAdd(&cnt[d.y], 1);
    atomicAdd(&cnt[d.z], 1);
    atomicAdd(&cnt[d.w], 1);
  } else {
    for (; i < N_EDGES; ++i) atomicAdd(&cnt[dst[i]], 1);
  }
}

__global__ void dinv_kernel(const int* __restrict__ cnt, float* __restrict__ dinv) {
  int v = blockIdx.x * blockDim.x + threadIdx.x;
  if (v < N_NODES) dinv[v] = rsqrtf((float)cnt[v] + 1.0f);
}

// exclusive scan of cnt[0..N) into rowptr[0..N); 1024 elems/block
__global__ void scan1_kernel(const int* __restrict__ in, int* __restrict__ out,
                             int* __restrict__ bsum) {
  __shared__ int ls[256];
  int t = threadIdx.x;
  int base = blockIdx.x * 1024 + t * 4;
  int a0 = (base + 0 < N_NODES) ? in[base + 0] : 0;
  int a1 = (base + 1 < N_NODES) ? in[base + 1] : 0;
  int a2 = (base + 2 < N_NODES) ? in[base + 2] : 0;
  int a3 = (base + 3 < N_NODES) ? in[base + 3] : 0;
  ls[t] = a0 + a1 + a2 + a3;
  __syncthreads();
  for (int off = 1; off < 256; off <<= 1) {
    int add = (t >= off) ? ls[t - off] : 0;
    __syncthreads();
    ls[t] += add;
    __syncthreads();
  }
  int excl = (t > 0) ? ls[t - 1] : 0;
  if (base + 0 < N_NODES) out[base + 0] = excl;
  if (base + 1 < N_NODES) out[base + 1] = excl + a0;
  if (base + 2 < N_NODES) out[base + 2] = excl + a0 + a1;
  if (base + 3 < N_NODES) out[base + 3] = excl + a0 + a1 + a2;
  if (t == 255) bsum[blockIdx.x] = ls[255];
}

__global__ void scan2_kernel(int* bsum, int nb) {
  if (threadIdx.x == 0 && blockIdx.x == 0) {
    int a = 0;
    for (int i = 0; i < nb; ++i) { int v = bsum[i]; bsum[i] = a; a += v; }
  }
}

// finalize rowptr AND initialize pos=rowptr (kills the d2d memcpy)
__global__ void scan3_kernel(int* __restrict__ out, const int* __restrict__ bsum,
                             int* __restrict__ pos) {
  int t = threadIdx.x;
  int base = blockIdx.x * 1024 + t * 4;
  int add = bsum[blockIdx.x];
  #pragma unroll
  for (int i = 0; i < 4; ++i)
    if (base + i < N_NODES) {
      int v = out[base + i] + add;
      out[base + i] = v;
      pos[base + i] = v;
    }
  if (blockIdx.x == 0 && t == 0) out[N_NODES] = N_EDGES;
}

// scatter edges into CSR slots (no Ssum atomic anymore)
__global__ void fill_kernel(const int* __restrict__ src, const int* __restrict__ dst,
                            const float* __restrict__ dinv, int* __restrict__ pos,
                            int2* __restrict__ csr) {
  int e = blockIdx.x * blockDim.x + threadIdx.x;
  if (e >= N_EDGES) return;
  int s = src[e], d = dst[e];
  float w = dinv[s] * dinv[d];
  int p = atomicAdd(&pos[d], 1);
  csr[p] = make_int2(s, __float_as_int(w));
}

// Ssum[v] = dinv[v]^2 + sum of incoming edge weights (coalesced-ish CSR read)
__global__ void ssum_kernel(const int2* __restrict__ csr, const int* __restrict__ rowptr,
                            const float* __restrict__ dinv, float* __restrict__ Ssum) {
  int v = blockIdx.x * blockDim.x + threadIdx.x;
  if (v >= N_NODES) return;
  float s = dinv[v] * dinv[v];
  int e1 = rowptr[v + 1];
  for (int e = rowptr[v]; e < e1; ++e) s += __int_as_float(csr[e].y);
  Ssum[v] = s;
}

// ---------------- per-layer GEMM: H[N,64] = X[N,K] @ W[K,64] ----------------

__global__ __launch_bounds__(256) void gemm_kernel(
    const float* __restrict__ X, const float* __restrict__ W,
    float* __restrict__ Hout, int K) {
  __shared__ float xs[64][81];   // [row][k], pad 81 to break 4-way bank conflict
  __shared__ float ws[80][64];   // [k][col]
  int t = threadIdx.x;
  int rowBase = blockIdx.x * 64;
  for (int i = t; i < K * 64; i += 256) ws[i >> 6][i & 63] = W[i];
  for (int i = t; i < 64 * K; i += 256) {
    int r = i / K, k = i - r * K;
    int row = rowBase + r;
    xs[r][k] = (row < N_NODES) ? X[(size_t)row * K + k] : 0.f;
  }
  __syncthreads();
  int ty = t >> 4, tx = t & 15;
  int r0 = ty * 4, c0 = tx * 4;
  float acc[4][4] = {};
  for (int k = 0; k < K; ++k) {
    float4 bq = *(const float4*)&ws[k][c0];
    float bv[4] = {bq.x, bq.y, bq.z, bq.w};
    float av[4] = {xs[r0][k], xs[r0 + 1][k], xs[r0 + 2][k], xs[r0 + 3][k]};
    #pragma unroll
    for (int i = 0; i < 4; ++i)
      #pragma unroll
      for (int j = 0; j < 4; ++j)
        acc[i][j] = fmaf(av[i], bv[j], acc[i][j]);
  }
  #pragma unroll
  for (int i = 0; i < 4; ++i) {
    int row = rowBase + r0 + i;
    if (row < N_NODES)
      *(float4*)&Hout[(size_t)row * HID + c0] =
          make_float4(acc[i][0], acc[i][1], acc[i][2], acc[i][3]);
  }
}

// ---------------- aggregation + relu + BN-stats ----------------
// z[v] = relu( sum_in w_e*H[src] + dinv^2*H[v] + S[v]*c + b );  stats += (z, z^2)
// 2 nodes per wave (32 lanes x float2 each) + 4x edge unroll => ~8 gather streams/wave

#define AGG_WAVES 8
#define AGG_PAIRS 4   // pairs per wave -> 8 nodes/wave, 64 nodes/block

__global__ __launch_bounds__(512) void agg_kernel(
    const float* __restrict__ H, const int2* __restrict__ csr,
    const int* __restrict__ rowptr, const float* __restrict__ S,
    const float* __restrict__ dinv, const float* __restrict__ cvec,
    const float* __restrict__ bias, float* __restrict__ Z,
    float* __restrict__ stats) {
  int t = threadIdx.x;
  int wave = t >> 6, lane = t & 63;
  int half = lane >> 5, li = lane & 31;
  int f = li * 2;
  int nodeBase = blockIdx.x * (AGG_WAVES * AGG_PAIRS * 2) + wave * (AGG_PAIRS * 2) + half;
  float2 cl = *(const float2*)&cvec[f];
  float2 bl = *(const float2*)&bias[f];
  float2 ssum = make_float2(0.f, 0.f), ssq = make_float2(0.f, 0.f);
  #pragma unroll
  for (int i = 0; i < AGG_PAIRS; ++i) {
    int v = nodeBase + 2 * i;
    if (v < N_NODES) {
      float dv = dinv[v];
      float2 hv = *(const float2*)&H[(size_t)v * HID + f];
      float sc = dv * dv;
      float2 acc = make_float2(hv.x * sc, hv.y * sc);
      int e0 = rowptr[v], e1 = rowptr[v + 1];
      int e = e0;
      for (; e + 4 <= e1; e += 4) {
        int2 p0 = csr[e + 0];
        int2 p1 = csr[e + 1];
        int2 p2 = csr[e + 2];
        int2 p3 = csr[e + 3];
        float2 h0 = *(const float2*)&H[(size_t)p0.x * HID + f];
        float2 h1 = *(const float2*)&H[(size_t)p1.x * HID + f];
        float2 h2 = *(const float2*)&H[(size_t)p2.x * HID + f];
        float2 h3 = *(const float2*)&H[(size_t)p3.x * HID + f];
        float w0 = __int_as_float(p0.y), w1 = __int_as_float(p1.y);
        float w2 = __int_as_float(p2.y), w3 = __int_as_float(p3.y);
        acc.x = fmaf(w0, h0.x, fmaf(w1, h1.x, fmaf(w2, h2.x, fmaf(w3, h3.x, acc.x))));
        acc.y = fmaf(w0, h0.y, fmaf(w1, h1.y, fmaf(w2, h2.y, fmaf(w3, h3.y, acc.y))));
      }
      for (; e < e1; ++e) {
        int2 p = csr[e];
        float2 h = *(const float2*)&H[(size_t)p.x * HID + f];
        float w = __int_as_float(p.y);
        acc.x = fmaf(w, h.x, acc.x);
        acc.y = fmaf(w, h.y, acc.y);
      }
      float sv = S[v];
      float2 z = make_float2(fmaxf(fmaf(sv, cl.x, acc.x + bl.x), 0.f),
                             fmaxf(fmaf(sv, cl.y, acc.y + bl.y), 0.f));
      *(float2*)&Z[(size_t)v * HID + f] = z;
      ssum.x += z.x; ssum.y += z.y;
      ssq.x += z.x * z.x; ssq.y += z.y * z.y;
    }
  }
  __shared__ float redS[AGG_WAVES * 2][64];
  __shared__ float redQ[AGG_WAVES * 2][64];
  redS[wave * 2 + half][f] = ssum.x;
  redS[wave * 2 + half][f + 1] = ssum.y;
  redQ[wave * 2 + half][f] = ssq.x;
  redQ[wave * 2 + half][f + 1] = ssq.y;
  __syncthreads();
  if (wave == 0) {
    float s = 0.f, q = 0.f;
    #pragma unroll
    for (int i = 0; i < AGG_WAVES * 2; ++i) { s += redS[i][lane]; q += redQ[i][lane]; }
    float* sl = stats + (size_t)(blockIdx.x & (NSLICE - 1)) * 128;
    atomicAdd(&sl[lane], s);
    atomicAdd(&sl[64 + lane], q);
  }
}

// ---------------- BN fold: alpha/beta, W' = alpha⊙W_next, c = beta@W_next ----

__global__ __launch_bounds__(256) void prep_kernel(
    const float* __restrict__ stats, const float* __restrict__ g,
    const float* __restrict__ be, const float* __restrict__ Wnext,
    float* __restrict__ Wp, float* __restrict__ cvec,
    float* __restrict__ ab, int hasNext) {
  __shared__ float tmp[128];
  __shared__ float alpha[64];
  __shared__ float beta[64];
  int t = threadIdx.x;
  if (t < 128) {
    float s = 0.f;
    for (int i = 0; i < NSLICE; ++i) s += stats[(size_t)i * 128 + t];
    tmp[t] = s;
  }
  __syncthreads();
  if (t < 64) {
    float m = tmp[t] / (float)N_NODES;
    float var = tmp[64 + t] / (float)N_NODES - m * m;
    float a = g[t] * rsqrtf(var + BN_EPS);
    alpha[t] = a;
    float bt = be[t] - m * a;
    beta[t] = bt;
    ab[t] = a;
    ab[64 + t] = bt;
  }
  __syncthreads();
  if (hasNext) {
    for (int i = t; i < HID * HID; i += 256) Wp[i] = alpha[i >> 6] * Wnext[i];
    if (t < 64) {
      float c = 0.f;
      for (int k = 0; k < HID; ++k) c += beta[k] * Wnext[k * HID + t];
      cvec[t] = c;
    }
  }
}

// ---------------- pool: out[g] += BN(z4)[v] for v in graph g (batch sorted) ----

#define POOL_CH 32

__global__ __launch_bounds__(256) void pool_kernel(
    const float* __restrict__ Z, const int* __restrict__ batch,
    const float* __restrict__ ab, float* __restrict__ out) {
  int tid = blockIdx.x * blockDim.x + threadIdx.x;
  int w = tid >> 6, lane = tid & 63;
  int v0 = w * POOL_CH;
  if (v0 >= N_NODES) return;
  int v1 = min(N_NODES, v0 + POOL_CH);
  float a = ab[lane], b = ab[64 + lane];
  float acc = 0.f;
  int cur = batch[v0];
  for (int v = v0; v < v1; ++v) {
    int bg = batch[v];
    if (bg != cur) {
      atomicAdd(&out[(size_t)cur * HID + lane], acc);
      acc = 0.f;
      cur = bg;
    }
    acc = fmaf(Z[(size_t)v * HID + lane], a, acc + b);
  }
  atomicAdd(&out[(size_t)cur * HID + lane], acc);
}

// ---------------- launch ----------------

extern "C" void kernel_launch(void* const* d_in, const int* in_sizes, int n_in,
                              void* d_out, int out_size, void* d_ws, size_t ws_size,
                              hipStream_t stream) {
  const float* x    = (const float*)d_in[0];
  const int* src    = (const int*)d_in[1];
  const int* dst    = (const int*)d_in[2];
  const int* batch  = (const int*)d_in[3];
  const float* W[4]  = {(const float*)d_in[4], (const float*)d_in[8],
                        (const float*)d_in[12], (const float*)d_in[16]};
  const float* b[4]  = {(const float*)d_in[5], (const float*)d_in[9],
                        (const float*)d_in[13], (const float*)d_in[17]};
  const float* g[4]  = {(const float*)d_in[6], (const float*)d_in[10],
                        (const float*)d_in[14], (const float*)d_in[18]};
  const float* be[4] = {(const float*)d_in[7], (const float*)d_in[11],
                        (const float*)d_in[15], (const float*)d_in[19]};

  char* wsb = (char*)d_ws;
  size_t off = 0;
  auto alloc = [&](size_t bytes) -> void* {
    void* p = wsb + off;
    off += (bytes + 255) & ~(size_t)255;
    return p;
  };
  // zeroed region (one memset)
  int*   cnt    = (int*)  alloc((N_NODES + 1) * 4);
  float* c0     = (float*)alloc(64 * 4);
  float* stats  = (float*)alloc((size_t)4 * NSLICE * 128 * 4);
  size_t zero_bytes = off;
  // non-zeroed
  float* Ssum   = (float*)alloc((size_t)N_NODES * 4);
  int*   rowptr = (int*)  alloc((size_t)(N_NODES + 1) * 4);
  int*   pos    = (int*)  alloc((size_t)N_NODES * 4);
  int*   bsum   = (int*)  alloc(128 * 4);
  float* dinv   = (float*)alloc((size_t)N_NODES * 4);
  int2*  csr    = (int2*) alloc((size_t)N_EDGES * 8);
  float* Hb     = (float*)alloc((size_t)N_NODES * HID * 4);
  float* Zb     = (float*)alloc((size_t)N_NODES * HID * 4);
  float* Wp     = (float*)alloc(HID * HID * 4);
  float* cv     = (float*)alloc(64 * 4);
  float* ab     = (float*)alloc(128 * 4);

  hipMemsetAsync(d_ws, 0, zero_bytes, stream);
  hipMemsetAsync(d_out, 0, (size_t)out_size * 4, stream);

  count_kernel<<<(N_EDGES / 4 + 255) / 256, 256, 0, stream>>>(dst, cnt);
  dinv_kernel<<<(N_NODES + 255) / 256, 256, 0, stream>>>(cnt, dinv);
  int nscan = (N_NODES + 1023) / 1024;
  scan1_kernel<<<nscan, 256, 0, stream>>>(cnt, rowptr, bsum);
  scan2_kernel<<<1, 64, 0, stream>>>(bsum, nscan);
  scan3_kernel<<<nscan, 256, 0, stream>>>(rowptr, bsum, pos);
  fill_kernel<<<(N_EDGES + 255) / 256, 256, 0, stream>>>(src, dst, dinv, pos, csr);
  ssum_kernel<<<(N_NODES + 255) / 256, 256, 0, stream>>>(csr, rowptr, dinv, Ssum);

  int gemmBlocks = (N_NODES + 63) / 64;
  int aggBlocks  = (N_NODES + AGG_WAVES * AGG_PAIRS * 2 - 1) / (AGG_WAVES * AGG_PAIRS * 2);

  // layer 1 (K=75, c=0)
  gemm_kernel<<<gemmBlocks, 256, 0, stream>>>(x, W[0], Hb, N_FEAT);
  agg_kernel<<<aggBlocks, 512, 0, stream>>>(Hb, csr, rowptr, Ssum, dinv, c0, b[0], Zb, stats);
  prep_kernel<<<1, 256, 0, stream>>>(stats, g[0], be[0], W[1], Wp, cv, ab, 1);

  // layers 2..4
  for (int l = 1; l < 4; ++l) {
    gemm_kernel<<<gemmBlocks, 256, 0, stream>>>(Zb, Wp, Hb, HID);
    agg_kernel<<<aggBlocks, 512, 0, stream>>>(Hb, csr, rowptr, Ssum, dinv, cv, b[l], Zb,
                                              stats + (size_t)l * NSLICE * 128);
    prep_kernel<<<1, 256, 0, stream>>>(stats + (size_t)l * NSLICE * 128, g[l], be[l],
                                       (l < 3) ? W[l + 1] : nullptr, Wp, cv, ab,
                                       (l < 3) ? 1 : 0);
  }

  int poolBlocks = (N_NODES + 4 * POOL_CH - 1) / (4 * POOL_CH);
  pool_kernel<<<poolBlocks, 256, 0, stream>>>(Zb, batch, ab, (float*)d_out);
}